// Round 9
// baseline (148.150 us; speedup 1.0000x reference)
//
#include <hip/hip_runtime.h>
#include <hip/hip_fp16.h>

// NCC loss, fully fused, R9: R8 MFMA chains + leaner LDS traffic.
// 8-wide staging tasks (144, waves 0-2): 5 b128 stores/task vs 10 b64.
// 32-row raw slices (rows 24-31 zeroed once) -> unconditional A2 reads.
// Chains rebalanced {0,4},{1,5},{2,6,8},{3,7,9}. DC=40 (throughput-bound).
// Vols: [B=2][D=160][H=192][W=160] fp32. Out: scalar -mean(cc).

#define B_    2
#define D_    160
#define H_    192
#define W_    160
#define HW_   (H_*W_)

// LDS layout (float-word offsets)
#define RS    20                   // raw row stride (taps 0..23 = dw 0..11; 12..19 zero pad)
#define SLS   (32*RS)              // 640: raw slice stride (rows 24..31 stay zero)
#define FS    (2*SLS)              // 1280: raw field stride
#define TMP0  (5*FS)               // 6400
#define TS    20                   // tmp col stride
#define HSUM0 (TMP0 + 4*320)       // 7680
#define HCS   160                  // per-(slc,f) hsum block
#define HRS   10                   // hsum col stride
#define REDU  (HSUM0 + 10*HCS)     // 9280
#define SMEM  (REDU + 8)           // 9288 dw = 37.2 KB -> 4 blocks/CU
#define DC    40
#define NMAC  24                   // (DC+8)/2
#define W3I   (1.0f/729.0f)
#define NTOT  9830400.0f

#if __has_builtin(__builtin_amdgcn_rcpf)
#define RCP(x) __builtin_amdgcn_rcpf(x)
#else
#define RCP(x) (1.0f/(x))
#endif
#define LGKM0() asm volatile("s_waitcnt lgkmcnt(0)" ::: "memory")

typedef _Float16 half8 __attribute__((ext_vector_type(8)));
typedef float    f32x4 __attribute__((ext_vector_type(4)));
#define MFMA16(a,b,c) __builtin_amdgcn_mfma_f32_16x16x32_f16((a),(b),(c),0,0,0)

struct __align__(8)  HP  { __half2 a, b; };        // 4 fp16 (b64)
struct __align__(16) HP4 { __half2 a, b, c, d; };  // 8 fp16 (b128)

__global__ __launch_bounds__(256, 4) void ncc_fused(const float* __restrict__ gI,
                                                    const float* __restrict__ gJ,
                                                    float* __restrict__ out)
{
  __shared__ __align__(16) float sm[SMEM];
  const int tid  = threadIdx.x;
  const int lane = tid & 63;
  const int Q    = tid >> 6;
  const int n15  = lane & 15;          // MFMA: A-row m / B-col n / D-col
  const int q4   = lane >> 4;          // MFMA: k-group / D-row quad
  const int w0   = blockIdx.x * 16;
  const int h0   = blockIdx.y * 16;
  const int bz   = blockIdx.z;
  const int bb   = bz >> 2;
  const int d_lo = (bz & 3) * DC;

  // zero raw+tmp region: row pads, rows 24..31, invalid halo stay 0 forever
  for (int i = tid; i < TMP0; i += 256) sm[i] = 0.f;

  // banded selection fragment: SEL[j] = [n15 <= k <= n15+8], k = 8*q4+j
  half8 SEL;
  #pragma unroll
  for (int j = 0; j < 8; ++j) {
    const int k = 8*q4 + j;
    SEL[j] = (k >= n15 && k <= n15 + 8) ? (_Float16)1 : (_Float16)0;
  }

  // ---------- staging: 144 tasks = 2 slc x 24 r x 3 8-wide chunks ----------
  const bool tval = (tid < 144);
  bool rowv = false, hv0 = false, hv1 = false;
  int  lo = 0, sc = 0;
  const float *pI = gI, *pJ = gJ;
  if (tval) {
    sc = tid / 72;
    const int u = tid - sc*72;
    const int r = u / 3, ci = u - 3*r;
    const int gh = h0 - 4 + r;
    const int gw = w0 - 4 + 8*ci;
    rowv = (unsigned)gh < (unsigned)H_;
    hv0  = rowv && ((unsigned)gw < (unsigned)(W_-3));
    hv1  = rowv && ((unsigned)(gw+4) < (unsigned)(W_-3));
    lo   = sc*SLS + r*RS + 4*ci;
    const long off = ((long)(bb*D_ + (d_lo - 4 + sc))*H_ + gh)*(long)W_ + gw;
    pI = gI + off; pJ = gJ + off;
  }

  // ---------- chain bases: wave Q -> chains {Q, Q+4} (+{Q+6} for Q>=2) ----
  auto rb_of = [&](int c) { return (c % 5)*FS + (c / 5)*SLS; };
  const int cA = Q, cB = Q + 4, cC = Q + 6;
  const int rbA = rb_of(cA), rbB = rb_of(cB), rbC = rb_of(cC);
  const int hbA = HSUM0 + cA*HCS, hbB = HSUM0 + cB*HCS, hbC = HSUM0 + cC*HCS;
  const int tb  = TMP0 + Q*320 + n15*TS;
  const int a1r = n15*RS + 4*q4;
  const int a2r = (16 + n15)*RS + 4*q4;   // rows 24..31 are zeros

  // ---------- ring: thread owns (h = tid>>4, w = tid&15) ----------
  const int rh = tid >> 4, rw = tid & 15;
  const int rbase = HSUM0 + rw*HRS + (rh >> 1);
  const int rsh   = (rh & 1) * 16;

  float ring[5][9], S[5];
  #pragma unroll
  for (int f = 0; f < 5; ++f) {
    S[f] = 0.f;
    #pragma unroll
    for (int k = 0; k < 9; ++k) ring[f][k] = 0.f;
  }
  float acc = 0.f;

  // ---------- global prefetch (4 float4 per staging task) ----------
  float4 ai0 = {0,0,0,0}, ai1 = {0,0,0,0}, aj0 = {0,0,0,0}, aj1 = {0,0,0,0};
  auto fetch = [&](int sbase) {
    const bool dv = tval && ((unsigned)(sbase + sc) < (unsigned)D_);
    const bool v0 = dv && hv0, v1 = dv && hv1;
    ai0 = v0 ? *(const float4*)pI       : make_float4(0,0,0,0);
    ai1 = v1 ? *(const float4*)(pI + 4) : make_float4(0,0,0,0);
    aj0 = v0 ? *(const float4*)pJ       : make_float4(0,0,0,0);
    aj1 = v1 ? *(const float4*)(pJ + 4) : make_float4(0,0,0,0);
    pI += 2*HW_; pJ += 2*HW_;
  };

  auto stage_write = [&]() {
    if (!(tval && rowv)) return;
    const __half2 iA = __floats2half2_rn(ai0.x, ai0.y);
    const __half2 iB = __floats2half2_rn(ai0.z, ai0.w);
    const __half2 iC = __floats2half2_rn(ai1.x, ai1.y);
    const __half2 iD = __floats2half2_rn(ai1.z, ai1.w);
    const __half2 jA = __floats2half2_rn(aj0.x, aj0.y);
    const __half2 jB = __floats2half2_rn(aj0.z, aj0.w);
    const __half2 jC = __floats2half2_rn(aj1.x, aj1.y);
    const __half2 jD = __floats2half2_rn(aj1.z, aj1.w);
    HP4 hI; hI.a = iA; hI.b = iB; hI.c = iC; hI.d = iD;
    HP4 hJ; hJ.a = jA; hJ.b = jB; hJ.c = jC; hJ.d = jD;
    HP4 h2; h2.a = __hmul2(iA,iA); h2.b = __hmul2(iB,iB);
            h2.c = __hmul2(iC,iC); h2.d = __hmul2(iD,iD);
    HP4 h3; h3.a = __hmul2(jA,jA); h3.b = __hmul2(jB,jB);
            h3.c = __hmul2(jC,jC); h3.d = __hmul2(jD,jD);
    HP4 h4; h4.a = __hmul2(iA,jA); h4.b = __hmul2(iB,jB);
            h4.c = __hmul2(iC,jC); h4.d = __hmul2(iD,jD);
    *(HP4*)&sm[lo]        = hI;
    *(HP4*)&sm[lo +   FS] = hJ;
    *(HP4*)&sm[lo + 2*FS] = h2;
    *(HP4*)&sm[lo + 3*FS] = h3;
    *(HP4*)&sm[lo + 4*FS] = h4;
  };

  // ---------- one chain: raw field slice -> hsum (2 w-MFMAs + 1 h-MFMA) ----
  auto chain = [&](int rb, int hb) {
    const half8 A1 = *(const half8*)&sm[rb + a1r];
    const half8 A2 = *(const half8*)&sm[rb + a2r];
    const f32x4 z = {0.f, 0.f, 0.f, 0.f};
    const f32x4 d1 = MFMA16(A1, SEL, z);      // wsum rows 0..15
    const f32x4 d2 = MFMA16(A2, SEL, z);      // wsum rows 16..23 (24..31 = 0)
    HP p1; p1.a = __floats2half2_rn(d1[0], d1[1]); p1.b = __floats2half2_rn(d1[2], d1[3]);
    HP p2; p2.a = __floats2half2_rn(d2[0], d2[1]); p2.b = __floats2half2_rn(d2[2], d2[3]);
    *(HP*)&sm[tb + 2*q4]     = p1;            // tmp col n15, k = 4q4..4q4+3
    *(HP*)&sm[tb + 8 + 2*q4] = p2;            // k = 16+4q4..19+4q4
    LGKM0();                                  // tmp visible to own wave
    const half8 Bh = *(const half8*)&sm[tb + 4*q4];   // col n15, k = 8q4..8q4+7
    const f32x4 dh = MFMA16(SEL, Bh, z);      // hsum[m = h][n = w]
    HP ph; ph.a = __floats2half2_rn(dh[0], dh[1]); ph.b = __floats2half2_rn(dh[2], dh[3]);
    *(HP*)&sm[hb + n15*HRS + 2*q4] = ph;      // col w = n15, h = 4q4..4q4+3
  };

  auto h2ext = [&](int addr) -> float {
    const unsigned u = *(const unsigned*)&sm[addr];
    return __half2float(__ushort_as_half((unsigned short)(u >> rsh)));
  };
  auto ring_cc = [&](int m) {
    float nA[5], nB[5];
    #pragma unroll
    for (int f = 0; f < 5; ++f) {
      nA[f] = h2ext(rbase + f*HCS);           // slice A = chain f
      nB[f] = h2ext(rbase + (5 + f)*HCS);     // slice B = chain 5+f
    }
    float SA[5], SB[5];
    #pragma unroll
    for (int f = 0; f < 5; ++f) {
      SA[f] = S[f]  + nA[f] - ring[f][8];
      SB[f] = SA[f] + nB[f] - ring[f][7];
      S[f]  = SB[f];
      #pragma unroll
      for (int k = 8; k >= 2; --k) ring[f][k] = ring[f][k-2];
      ring[f][1] = nA[f]; ring[f][0] = nB[f];
    }
    if (m >= 4) {
      {
        const float cr = SA[4] - SA[0]*SA[1]*W3I;
        const float vi = SA[2] - SA[0]*SA[0]*W3I;
        const float vj = SA[3] - SA[1]*SA[1]*W3I;
        acc += cr*cr * RCP(vi*vj + 1e-5f);
      }
      {
        const float cr = SB[4] - SB[0]*SB[1]*W3I;
        const float vi = SB[2] - SB[0]*SB[0]*W3I;
        const float vj = SB[3] - SB[1]*SB[1]*W3I;
        acc += cr*cr * RCP(vi*vj + 1e-5f);
      }
    }
  };

  fetch(d_lo - 4);          // macro 0 slices
  __syncthreads();          // zero-init visible
  stage_write();            // raw macro 0
  fetch(d_lo - 2);          // macro 1 slices
  __syncthreads();          // raw 0 ready

  for (int m = 0; m < NMAC; ++m) {
    chain(rbA, hbA);
    chain(rbB, hbB);
    if (Q >= 2) chain(rbC, hbC);
    __syncthreads();                       // hsum (all waves) ready
    ring_cc(m);
    if (m + 1 < NMAC) { stage_write(); fetch(d_lo + 2*m); }  // raw m+1; regs m+2
    __syncthreads();                       // raw m+1 ready; hsum consumed
  }

  // ---- block reduction -> single atomic ----
  float v = acc;
  #pragma unroll
  for (int off = 32; off > 0; off >>= 1)
    v += __shfl_down(v, off, 64);
  if (lane == 0) sm[REDU + Q] = v;
  __syncthreads();
  if (tid == 0) {
    const float t = sm[REDU] + sm[REDU+1] + sm[REDU+2] + sm[REDU+3];
    atomicAdd(out, -t / NTOT);
  }
}

extern "C" void kernel_launch(void* const* d_in, const int* in_sizes, int n_in,
                              void* d_out, int out_size, void* d_ws, size_t ws_size,
                              hipStream_t stream) {
  const float* J = (const float*)d_in[0];  // y_pred
  const float* I = (const float*)d_in[1];  // y_true (cc symmetric in I,J)
  float* outp = (float*)d_out;
  hipMemsetAsync(d_out, 0, sizeof(float), stream);
  dim3 grid(W_/16, H_/16, B_*4);           // 10 x 12 x 8 = 960 blocks
  ncc_fused<<<grid, dim3(256), 0, stream>>>(I, J, outp);
}